// Round 1
// baseline (1523.462 us; speedup 1.0000x reference)
//
#include <hip/hip_runtime.h>
#include <hip/hip_bf16.h>

#define TPB 256
#define TK_CAP 2048
#define BAND_CAP 256
#define TK_EPS 0.06f
#define TK_THR 1.75f

typedef __attribute__((ext_vector_type(4))) float f32x4;
typedef __bf16 bf16x8 __attribute__((ext_vector_type(8)));

__device__ __forceinline__ unsigned short bf16_bits(__bf16 h) {
  return __builtin_bit_cast(unsigned short, h);
}

// async global->LDS, 16B per lane. LDS dest must be wave-uniform base;
// HW writes lane i's 16B at base + i*16 (m97-verified pattern).
__device__ __forceinline__ void gload16(const bf16x8* g, bf16x8* l) {
  __builtin_amdgcn_global_load_lds(
      (const __attribute__((address_space(1))) unsigned int*)g,
      (__attribute__((address_space(3))) unsigned int*)l, 16, 0, 0);
}

// wave-cooperative fp64 dot of LDS xs[] with global fp32 row wr[].
// D==768 path: 12 loads issued back-to-back (one vmcnt drain per dot).
__device__ __forceinline__ double dot_w64(const double* xs, const float* wr,
                                          int lane, int D) {
  double sum = 0.0;
  if ((D >> 6) == 12) {
    float wv[12];
#pragma unroll
    for (int u = 0; u < 12; ++u) wv[u] = wr[lane + (u << 6)];
#pragma unroll
    for (int u = 0; u < 12; ++u) sum += xs[lane + (u << 6)] * (double)wv[u];
  } else {
    for (int d = lane; d < D; d += 64) sum += xs[d] * (double)wr[d];
  }
#pragma unroll
  for (int m = 32; m > 0; m >>= 1) sum += __shfl_xor(sum, m, 64);
  return sum;
}

// wave-cooperative fp32 dot of two global rows (same ILP trick).
__device__ __forceinline__ float dotf_w64(const float* a, const float* b,
                                          int lane, int D) {
  float s = 0.f;
  if ((D >> 6) == 12) {
    float av[12], bv[12];
#pragma unroll
    for (int u = 0; u < 12; ++u) {
      av[u] = a[lane + (u << 6)];
      bv[u] = b[lane + (u << 6)];
    }
#pragma unroll
    for (int u = 0; u < 12; ++u) s += av[u] * bv[u];
  } else {
    for (int d = lane; d < D; d += 64) s += a[d] * b[d];
  }
#pragma unroll
  for (int m = 32; m > 0; m >>= 1) s += __shfl_xor(s, m, 64);
  return s;
}

// ---------------------------------------------------------------------------
// pack_tiles: fp32 [R,D] (optionally minus `sub`) -> bf16 tile-permuted
// layout [R/128][D/32][512] of bf16x8. Block (0,0) additionally zeroes the
// per-row candidate counters (stream-ordered before the GEMM that fills them).
// ---------------------------------------------------------------------------
__global__ __launch_bounds__(TPB) void pack_tiles(
    const float* __restrict__ src, const float* __restrict__ sub,
    bf16x8* __restrict__ dst, int D, unsigned* __restrict__ cntz, int nrows) {
  if (cntz && blockIdx.x == 0 && blockIdx.y == 0)
    for (int i = threadIdx.x; i < nrows; i += TPB) cntz[i] = 0u;
  const int r0 = blockIdx.x * 128;
  const int k0 = blockIdx.y * 32;
  const size_t tile = ((size_t)blockIdx.x * gridDim.y + blockIdx.y) * 512;
#pragma unroll
  for (int e = 0; e < 2; ++e) {
    const int q = e * 256 + threadIdx.x;
    const int row = q & 127, g = q >> 7;
    const float* s = src + (size_t)(r0 + row) * D + k0 + g * 8;
    f32x4 v0 = *(const f32x4*)s;
    f32x4 v1 = *(const f32x4*)(s + 4);
    if (sub) {
      const float* bp = sub + k0 + g * 8;
      v0 = v0 - *(const f32x4*)bp;
      v1 = v1 - *(const f32x4*)(bp + 4);
    }
    bf16x8 o;
#pragma unroll
    for (int u = 0; u < 4; ++u) o[u] = (__bf16)v0[u];
#pragma unroll
    for (int u = 0; u < 4; ++u) o[u + 4] = (__bf16)v1[u];
    dst[tile + q] = o;
  }
}

// ---------------------------------------------------------------------------
// pre = relu(A @ W^T + benc), pure bf16 MFMA, m97 structure.
// 128x128 tile, BK=32, 4 waves (2x2 of 64x64), pre stored bf16.
// Epilogue additionally appends candidates with bf16(v) > TK_THR to the
// per-row global list (top-64 threshold is ~2.78 for this data; ~985/row
// candidates expected, cap 2048) -- topk no longer re-reads the 50MB pre.
// ---------------------------------------------------------------------------
__global__ __launch_bounds__(TPB) void enc_gemm_bf(
    const bf16x8* __restrict__ A,   // packed [B/128][nkt][512]
    const bf16x8* __restrict__ W,   // packed [F/128][nkt][512]
    const float* __restrict__ benc,
    __bf16* __restrict__ pre,       // [B,F] bf16 (kept for fallback path)
    unsigned* __restrict__ cnt,     // [B] candidate counts
    unsigned* __restrict__ cand,    // [B][TK_CAP] packed (bf16bits<<16 | col)
    int nkt, int F) {
  __shared__ bf16x8 As[512], Ws[512];
  const int t = threadIdx.x;
  const int lane = t & 63, wv = t >> 6;
  const int wm = (wv >> 1) * 64, wn = (wv & 1) * 64;
  const int lrow = lane & 15, quad = lane >> 4;
  const size_t Ab = (size_t)blockIdx.y * nkt * 512;
  const size_t Wb = (size_t)blockIdx.x * nkt * 512;

  f32x4 acc[4][4];
#pragma unroll
  for (int i = 0; i < 4; ++i)
#pragma unroll
    for (int j = 0; j < 4; ++j) acc[i][j] = (f32x4){0.f, 0.f, 0.f, 0.f};

  for (int kt = 0; kt < nkt; ++kt) {
    __syncthreads();
    const bf16x8* ag = A + Ab + (size_t)kt * 512 + wv * 128;
    const bf16x8* wg = W + Wb + (size_t)kt * 512 + wv * 128;
    bf16x8* al = As + wv * 128;
    bf16x8* wl = Ws + wv * 128;
    gload16(ag + lane, al);
    gload16(ag + 64 + lane, al + 64);
    gload16(wg + lane, wl);
    gload16(wg + 64 + lane, wl + 64);
    __syncthreads();
    bf16x8 af[4];
#pragma unroll
    for (int i = 0; i < 4; ++i) af[i] = As[quad * 128 + wm + i * 16 + lrow];
#pragma unroll
    for (int j = 0; j < 4; ++j) {
      bf16x8 bfr = Ws[quad * 128 + wn + j * 16 + lrow];
#pragma unroll
      for (int i = 0; i < 4; ++i)
        acc[i][j] = __builtin_amdgcn_mfma_f32_16x16x32_bf16(af[i], bfr, acc[i][j], 0, 0, 0);
    }
  }
  const int bf0 = blockIdx.x * 128, bb = blockIdx.y * 128;
#pragma unroll
  for (int j = 0; j < 4; ++j) {
    const int col = bf0 + wn + j * 16 + lrow;
    const float bc = benc[col];
#pragma unroll
    for (int i = 0; i < 4; ++i) {
      const int row0 = bb + wm + i * 16 + quad * 4;
#pragma unroll
      for (int rg = 0; rg < 4; ++rg) {
        float v = acc[i][j][rg] + bc;
        v = v > 0.f ? v : 0.f;
        const __bf16 hb = (__bf16)v;
        pre[(size_t)(row0 + rg) * F + col] = hb;
        const unsigned ub = (unsigned)bf16_bits(hb);
        const float vb = __uint_as_float(ub << 16);
        if (vb > TK_THR) {
          const int r = row0 + rg;
          const unsigned p = atomicAdd(&cnt[r], 1u);
          if (p < TK_CAP) cand[(size_t)r * TK_CAP + p] = (ub << 16) | (unsigned)col;
        }
      }
    }
  }
}

// ---------------------------------------------------------------------------
// topk_sel2: top-64 selection matching exact-fp64 ranking, from the
// precollected candidate list (fast path; no pre re-read).
//  1. load n<=2048 packed (bf16bits<<16|col) candidates (4KB coalesced)
//  2. 2x8-bit radix over the 16 meaningful bits -> T = 64th-largest approx
//     (bin search = wave-parallel suffix scan, not serial 256-bin walk)
//  3. margin check: collection thr < T-eps certifies list completeness
//  4. > T+eps: sure-in, emit approx; [T-eps,T+eps]: exact fp64 rerank
// Fallback (n<64 / n>cap / margin fail): adaptive-threshold rescan of pre16,
// identical semantics to the previous passing kernel.
// ---------------------------------------------------------------------------
__global__ __launch_bounds__(TPB) void topk_sel2(
    const unsigned* __restrict__ cnt, const unsigned* __restrict__ cand,
    const unsigned short* __restrict__ pre,  // [B,F] bf16 bits (fallback only)
    const float* __restrict__ x, const float* __restrict__ W,
    const float* __restrict__ benc, const float* __restrict__ bdec,
    float* __restrict__ vals, int* __restrict__ idxs, int D, int F) {
  const int b = blockIdx.x;
  const int tid = threadIdx.x;

  __shared__ unsigned cpack[TK_CAP];
  __shared__ unsigned hist[256];
  __shared__ double xs[768];
  __shared__ int bcand[BAND_CAP];
  __shared__ double bexact[BAND_CAP];
  __shared__ int sh_cnt, sh_out, sh_band;
  __shared__ unsigned sh_prefix, sh_need;
  __shared__ float sh_thr;

  for (int d = tid; d < D; d += TPB)
    xs[d] = (double)x[(size_t)b * D + d] - (double)bdec[d];

  int n = 0;
  bool have = false;
  {
    const int nc = (int)cnt[b];
    if (nc >= 64 && nc <= TK_CAP) {
      for (int q = tid; q < nc; q += TPB) cpack[q] = cand[(size_t)b * TK_CAP + q];
      n = nc;
      have = true;
    }
  }
  if (tid == 0) sh_thr = TK_THR;
  __syncthreads();

  float T = 0.f;
  float step = 0.375f;
  for (int outer = 0; outer < 40; ++outer) {
    if (!have) {
      // fallback rescan (statistically unreachable for this data)
      const unsigned short* row = pre + (size_t)b * F;
      for (int tries = 0; tries < 40; ++tries) {
        if (tid == 0) sh_cnt = 0;
        __syncthreads();
        const float thr = sh_thr;
        for (int i = tid * 8; i < F; i += TPB * 8) {
          const uint4 pk = *(const uint4*)(row + i);
          const unsigned wb[4] = {pk.x, pk.y, pk.z, pk.w};
#pragma unroll
          for (int u = 0; u < 4; ++u) {
            const unsigned lo = wb[u] << 16;
            const unsigned hi = wb[u] & 0xFFFF0000u;
            if (__uint_as_float(lo) > thr) {
              int p = atomicAdd(&sh_cnt, 1);
              if (p < TK_CAP) cpack[p] = lo | (unsigned)(i + 2 * u);
            }
            if (__uint_as_float(hi) > thr) {
              int p = atomicAdd(&sh_cnt, 1);
              if (p < TK_CAP) cpack[p] = hi | (unsigned)(i + 2 * u + 1);
            }
          }
        }
        __syncthreads();
        n = sh_cnt;
        if (n >= 64 && n <= TK_CAP) break;
        if (tid == 0) sh_thr = (n < 64) ? sh_thr - step : sh_thr + step;
        step *= 0.5f;
        __syncthreads();
      }
      if (n > TK_CAP) n = TK_CAP;  // hang-safety clamp
    }

    // radix-select 64th largest over top-16 value bits (2 passes of 8)
    if (tid == 0) { sh_prefix = 0u; sh_need = 64u; }
#pragma unroll
    for (int pass = 0; pass < 2; ++pass) {
      const int shift = 24 - 8 * pass;
      hist[tid] = 0u;
      __syncthreads();
      const unsigned prefix = sh_prefix;
      const unsigned maskhi = pass == 0 ? 0u : 0xFF000000u;
      for (int q = tid; q < n; q += TPB) {
        const unsigned k = cpack[q];
        if ((k & maskhi) == prefix) atomicAdd(&hist[(k >> shift) & 255u], 1u);
      }
      __syncthreads();
      if (tid < 64) {
        // wave-parallel suffix scan: lane owns bins [4*tid, 4*tid+3]
        const unsigned h0 = hist[tid * 4], h1 = hist[tid * 4 + 1];
        const unsigned h2 = hist[tid * 4 + 2], h3 = hist[tid * 4 + 3];
        const unsigned lsum = h0 + h1 + h2 + h3;
        unsigned s = lsum;
#pragma unroll
        for (int off = 1; off < 64; off <<= 1) {
          const unsigned o = __shfl_down(s, off, 64);
          if (tid + off < 64) s += o;
        }
        const unsigned above = s - lsum;  // sum over lanes > tid
        const unsigned t3 = h3, t2 = h2 + t3, t1 = h1 + t2, t0 = h0 + t1;
        const unsigned suf[4] = {above + t0, above + t1, above + t2, above + t3};
        const unsigned hh[4] = {h0, h1, h2, h3};
        const unsigned need = sh_need;
#pragma unroll
        for (int u = 0; u < 4; ++u) {
          if (suf[u] >= need && suf[u] - hh[u] < need) {
            sh_prefix = prefix | ((unsigned)(tid * 4 + u) << shift);
            sh_need = need - (suf[u] - hh[u]);
          }
        }
      }
      __syncthreads();
    }
    T = __uint_as_float(sh_prefix);
    const float colthr = sh_thr;
    if (colthr < T - TK_EPS) break;  // completeness margin certified
    have = false;
    if (tid == 0) sh_thr = T - 2.f * TK_EPS;
    __syncthreads();
  }

  // classify collected
  if (tid == 0) { sh_out = 0; sh_band = 0; }
  __syncthreads();
  const float hicut = T + TK_EPS, locut = T - TK_EPS;
  float* ovals = vals + (size_t)b * 64;
  int* oidx = idxs + (size_t)b * 64;
  for (int q = tid; q < n; q += TPB) {
    const unsigned k = cpack[q];
    const float v = __uint_as_float(k & 0xFFFF0000u);
    const int id = (int)(k & 0xFFFFu);
    if (v > hicut) {
      int p = atomicAdd(&sh_out, 1);
      ovals[p] = v; oidx[p] = id;
    } else if (v >= locut) {
      int p = atomicAdd(&sh_band, 1);
      if (p < BAND_CAP) bcand[p] = id;
    }
  }
  __syncthreads();
  const int s = sh_out;
  const int bn = sh_band < BAND_CAP ? sh_band : BAND_CAP;
  const int needk = 64 - s;
  const int lane = tid & 63, wv = tid >> 6;
  for (int q = wv; q < bn; q += 4) {
    double sum = dot_w64(xs, W + (size_t)bcand[q] * D, lane, D);
    if (lane == 0) {
      double v = sum + (double)benc[bcand[q]];
      bexact[q] = v > 0.0 ? v : 0.0;
    }
  }
  __syncthreads();
  if (tid < bn) {
    const double v = bexact[tid];
    const int id = bcand[tid];
    int rank = 0;
    for (int j = 0; j < bn; ++j)
      rank += (bexact[j] > v) || (bexact[j] == v && bcand[j] < id);
    if (rank < needk) { ovals[s + rank] = (float)v; oidx[s + rank] = id; }
  }
}

// ---------------------------------------------------------------------------
// Transpose W_dec (D,F) -> (F,D)
// ---------------------------------------------------------------------------
__global__ __launch_bounds__(TPB) void transpose_df(
    const float* __restrict__ in, float* __restrict__ out, int D, int F) {
  __shared__ float tile[32][33];
  const int f0 = blockIdx.x * 32;
  const int d0 = blockIdx.y * 32;
  const int tx = threadIdx.x & 31;
  const int ty = threadIdx.x >> 5;
#pragma unroll
  for (int i = 0; i < 4; ++i)
    tile[ty + i * 8][tx] = in[(size_t)(d0 + ty + i * 8) * F + f0 + tx];
  __syncthreads();
#pragma unroll
  for (int i = 0; i < 4; ++i)
    out[(size_t)(f0 + ty + i * 8) * D + d0 + tx] = tile[tx][ty + i * 8];
}

// ---------------------------------------------------------------------------
// Sparse decode (float4): out[b,:] = bdec + sum_k vals[b,k] * WT[idx[b,k],:]
// ---------------------------------------------------------------------------
__global__ __launch_bounds__(TPB) void decode64(
    const float* __restrict__ WT, const float* __restrict__ bdec,
    const float* __restrict__ vals, const int* __restrict__ idxs,
    float* __restrict__ out, int D) {
  const int b = blockIdx.x;
  __shared__ float sv[64];
  __shared__ int si[64];
  const int tid = threadIdx.x;
  if (tid < 64) {
    sv[tid] = vals[(size_t)b * 64 + tid];
    si[tid] = idxs[(size_t)b * 64 + tid];
  }
  __syncthreads();
  const int nd4 = D >> 2;
  for (int d4 = tid; d4 < nd4; d4 += TPB) {
    f32x4 acc = *(const f32x4*)(bdec + d4 * 4);
#pragma unroll 8
    for (int k = 0; k < 64; ++k)
      acc += *(const f32x4*)(WT + (size_t)si[k] * D + d4 * 4) * sv[k];
    *(f32x4*)(out + (size_t)b * D + d4 * 4) = acc;
  }
}

// ---------------------------------------------------------------------------
// approx_acts: connection matching + wave-parallel cooperative dots
// ---------------------------------------------------------------------------
__global__ __launch_bounds__(TPB) void contrib(
    const int* __restrict__ conn, const float* __restrict__ Wencd,
    const float* __restrict__ WTdecu,
    const float* __restrict__ up_vals, const int* __restrict__ up_idx,
    const int* __restrict__ down_idx,
    float* __restrict__ approx, int D, int C) {
  const int b = blockIdx.x;
  __shared__ int sui[64];
  __shared__ float suv[64];
  __shared__ int sdi[64];
  __shared__ float sacc[64];
  __shared__ int queue[2048];
  __shared__ int qn;
  const int tid = threadIdx.x;
  if (tid < 64) {
    sui[tid] = up_idx[(size_t)b * 64 + tid];
    suv[tid] = up_vals[(size_t)b * 64 + tid];
    sdi[tid] = down_idx[(size_t)b * 64 + tid];
    sacc[tid] = 0.0f;
  }
  if (tid == 0) qn = 0;
  __syncthreads();
  const int npairs = 64 * C;
  for (int p = tid; p < npairs; p += TPB) {
    int kd = p / C, c = p - kd * C;
    int f = conn[(size_t)sdi[kd] * C + c];
    if (f < 0) continue;
    for (int ku = 0; ku < 64; ++ku) {
      if (sui[ku] == f) {  // up_idx distinct -> at most one match
        int q = atomicAdd(&qn, 1);
        queue[q] = (kd << 8) | ku;
        break;
      }
    }
  }
  __syncthreads();
  const int n = qn;
  const int lane = tid & 63, wv = tid >> 6;
  for (int q = wv; q < n; q += 4) {
    const int kd = queue[q] >> 8, ku = queue[q] & 255;
    float s = dotf_w64(Wencd + (size_t)sdi[kd] * D,
                       WTdecu + (size_t)sui[ku] * D, lane, D);
    if (lane == 0) atomicAdd(&sacc[kd], suv[ku] * s);
  }
  __syncthreads();
  if (tid < 64) approx[(size_t)b * 64 + tid] = sacc[tid];
}

// ---------------------------------------------------------------------------
extern "C" void kernel_launch(void* const* d_in, const int* in_sizes, int n_in,
                              void* d_out, int out_size, void* d_ws, size_t ws_size,
                              hipStream_t stream) {
  const float* x_up   = (const float*)d_in[0];
  const float* x_down = (const float*)d_in[1];
  const float* Wenc_u = (const float*)d_in[2];
  const float* benc_u = (const float*)d_in[3];
  const float* Wdec_u = (const float*)d_in[4];
  const float* bdec_u = (const float*)d_in[5];
  const float* Wenc_d = (const float*)d_in[6];
  const float* benc_d = (const float*)d_in[7];
  const float* Wdec_d = (const float*)d_in[8];
  const float* bdec_d = (const float*)d_in[9];
  const int*   conn   = (const int*)d_in[10];

  const int D = in_sizes[5];           // 768
  const int B = in_sizes[0] / D;       // 1024
  const int F = in_sizes[3];           // 24576
  const int C = in_sizes[10] / F;      // 32
  const int nkt = D / 32;              // 24

  float* out = (float*)d_out;
  char* w = (char*)d_ws;

  __bf16* pre16 = (__bf16*)w;
  bf16x8* Wperm = (bf16x8*)(w + (size_t)B * F * 2);
  bf16x8* xuP   = (bf16x8*)(w + (size_t)B * F * 2 + (size_t)F * D * 2);
  bf16x8* xdP   = xuP + (size_t)B * D / 8;
  float* up_vals = (float*)(xdP + (size_t)B * D / 8);
  int*   up_idx  = (int*)(up_vals + (size_t)B * 64);
  float* dn_vals = (float*)(up_idx + (size_t)B * 64);
  int*   dn_idx  = (int*)(dn_vals + (size_t)B * 64);
  float* approx  = (float*)(dn_idx + (size_t)B * 64);
  unsigned* cnt  = (unsigned*)(approx + (size_t)B * 64);   // [B]
  unsigned* cand = cnt + B;                                // [B][TK_CAP]
  float* WT = (float*)w;  // reuses pre+Wperm region after both are dead

  dim3 packW_grid(F / 128, nkt);
  dim3 packX_grid(B / 128, nkt);
  dim3 gemm_grid(F / 128, B / 128);
  dim3 tr_grid(F / 32, D / 32);

  // ---- upstream encode ----
  pack_tiles<<<packX_grid, TPB, 0, stream>>>(x_up, bdec_u, xuP, D, cnt, B);
  pack_tiles<<<packW_grid, TPB, 0, stream>>>(Wenc_u, nullptr, Wperm, D, nullptr, 0);
  enc_gemm_bf<<<gemm_grid, TPB, 0, stream>>>(xuP, Wperm, benc_u, pre16, cnt, cand, nkt, F);
  topk_sel2<<<B, TPB, 0, stream>>>(cnt, cand, (const unsigned short*)pre16, x_up,
                                   Wenc_u, benc_u, bdec_u, up_vals, up_idx, D, F);
  // ---- downstream encode ----
  pack_tiles<<<packX_grid, TPB, 0, stream>>>(x_down, bdec_d, xdP, D, cnt, B);
  pack_tiles<<<packW_grid, TPB, 0, stream>>>(Wenc_d, nullptr, Wperm, D, nullptr, 0);
  enc_gemm_bf<<<gemm_grid, TPB, 0, stream>>>(xdP, Wperm, benc_d, pre16, cnt, cand, nkt, F);
  topk_sel2<<<B, TPB, 0, stream>>>(cnt, cand, (const unsigned short*)pre16, x_down,
                                   Wenc_d, benc_d, bdec_d, dn_vals, dn_idx, D, F);

  // ---- decode + contributions ----
  transpose_df<<<tr_grid, TPB, 0, stream>>>(Wdec_u, WT, D, F);
  decode64<<<B, TPB, 0, stream>>>(WT, bdec_u, up_vals, up_idx, out, D);
  contrib<<<B, TPB, 0, stream>>>(conn, Wenc_d, WT, up_vals, up_idx, dn_idx,
                                 approx, D, C);
  transpose_df<<<tr_grid, TPB, 0, stream>>>(Wdec_d, WT, D, F);
  decode64<<<B, TPB, 0, stream>>>(WT, bdec_d, approx, dn_idx, out + (size_t)B * D, D);
}

// Round 2
// 654.737 us; speedup vs baseline: 2.3268x; 2.3268x over previous
//
#include <hip/hip_runtime.h>
#include <hip/hip_bf16.h>

#define TPB 256
#define TK_CAP 2048
#define BAND_CAP 256
#define TK_EPS 0.06f
#define TK_THR 1.75f
#define ROWCAP 24  // per-row per-block candidate cap (mean ~5.1, 8-sigma safe)

typedef __attribute__((ext_vector_type(4))) float f32x4;
typedef __bf16 bf16x8 __attribute__((ext_vector_type(8)));

__device__ __forceinline__ unsigned short bf16_bits(__bf16 h) {
  return __builtin_bit_cast(unsigned short, h);
}

// async global->LDS, 16B per lane. LDS dest must be wave-uniform base;
// HW writes lane i's 16B at base + i*16 (m97-verified pattern).
__device__ __forceinline__ void gload16(const bf16x8* g, bf16x8* l) {
  __builtin_amdgcn_global_load_lds(
      (const __attribute__((address_space(1))) unsigned int*)g,
      (__attribute__((address_space(3))) unsigned int*)l, 16, 0, 0);
}

// wave-cooperative fp64 dot of LDS xs[] with global fp32 row wr[].
__device__ __forceinline__ double dot_w64(const double* xs, const float* wr,
                                          int lane, int D) {
  double sum = 0.0;
  if ((D >> 6) == 12) {
    float wv[12];
#pragma unroll
    for (int u = 0; u < 12; ++u) wv[u] = wr[lane + (u << 6)];
#pragma unroll
    for (int u = 0; u < 12; ++u) sum += xs[lane + (u << 6)] * (double)wv[u];
  } else {
    for (int d = lane; d < D; d += 64) sum += xs[d] * (double)wr[d];
  }
#pragma unroll
  for (int m = 32; m > 0; m >>= 1) sum += __shfl_xor(sum, m, 64);
  return sum;
}

// wave-cooperative fp32 dot of two global rows (same ILP trick).
__device__ __forceinline__ float dotf_w64(const float* a, const float* b,
                                          int lane, int D) {
  float s = 0.f;
  if ((D >> 6) == 12) {
    float av[12], bv[12];
#pragma unroll
    for (int u = 0; u < 12; ++u) {
      av[u] = a[lane + (u << 6)];
      bv[u] = b[lane + (u << 6)];
    }
#pragma unroll
    for (int u = 0; u < 12; ++u) s += av[u] * bv[u];
  } else {
    for (int d = lane; d < D; d += 64) s += a[d] * b[d];
  }
#pragma unroll
  for (int m = 32; m > 0; m >>= 1) s += __shfl_xor(s, m, 64);
  return s;
}

// ---------------------------------------------------------------------------
// pack_tiles: fp32 [R,D] (optionally minus `sub`) -> bf16 tile-permuted
// layout [R/128][D/32][512] of bf16x8. Block (0,0) additionally zeroes the
// per-row candidate counters (stream-ordered before the GEMM that fills them).
// ---------------------------------------------------------------------------
__global__ __launch_bounds__(TPB) void pack_tiles(
    const float* __restrict__ src, const float* __restrict__ sub,
    bf16x8* __restrict__ dst, int D, unsigned* __restrict__ cntz, int nrows) {
  if (cntz && blockIdx.x == 0 && blockIdx.y == 0)
    for (int i = threadIdx.x; i < nrows; i += TPB) cntz[i] = 0u;
  const int r0 = blockIdx.x * 128;
  const int k0 = blockIdx.y * 32;
  const size_t tile = ((size_t)blockIdx.x * gridDim.y + blockIdx.y) * 512;
#pragma unroll
  for (int e = 0; e < 2; ++e) {
    const int q = e * 256 + threadIdx.x;
    const int row = q & 127, g = q >> 7;
    const float* s = src + (size_t)(r0 + row) * D + k0 + g * 8;
    f32x4 v0 = *(const f32x4*)s;
    f32x4 v1 = *(const f32x4*)(s + 4);
    if (sub) {
      const float* bp = sub + k0 + g * 8;
      v0 = v0 - *(const f32x4*)bp;
      v1 = v1 - *(const f32x4*)(bp + 4);
    }
    bf16x8 o;
#pragma unroll
    for (int u = 0; u < 4; ++u) o[u] = (__bf16)v0[u];
#pragma unroll
    for (int u = 0; u < 4; ++u) o[u + 4] = (__bf16)v1[u];
    dst[tile + q] = o;
  }
}

// ---------------------------------------------------------------------------
// pre = relu(A @ W^T + benc), pure bf16 MFMA, m97 structure.
// 128x128 tile, BK=32, 4 waves (2x2 of 64x64), pre stored bf16.
// Epilogue collects candidates with bf16(v) > TK_THR into a per-row LDS list
// (cheap LDS atomics), then flushes with ONE global atomicAdd per row per
// block (128 concurrent atomics, one latency round-trip) + short copy.
// Round-1 lesson: per-hit global atomics serialized ~60 L2 round-trips per
// wave in the epilogue (600us, MfmaUtil 2.5%). LDS aggregation removes that.
// Per-row/per-block overflow (>ROWCAP) poisons cnt[row] past TK_CAP, routing
// topk_sel2 to its exact fallback rescan of pre16 -- semantics unchanged.
// ---------------------------------------------------------------------------
__global__ __launch_bounds__(TPB) void enc_gemm_bf(
    const bf16x8* __restrict__ A,   // packed [B/128][nkt][512]
    const bf16x8* __restrict__ W,   // packed [F/128][nkt][512]
    const float* __restrict__ benc,
    __bf16* __restrict__ pre,       // [B,F] bf16 (kept for fallback path)
    unsigned* __restrict__ cnt,     // [B] candidate counts
    unsigned* __restrict__ cand,    // [B][TK_CAP] packed (bf16bits<<16 | col)
    int nkt, int F) {
  __shared__ bf16x8 As[512], Ws[512];
  __shared__ unsigned candL[128 * ROWCAP];
  __shared__ unsigned cntL[128];
  const int t = threadIdx.x;
  const int lane = t & 63, wv = t >> 6;
  const int wm = (wv >> 1) * 64, wn = (wv & 1) * 64;
  const int lrow = lane & 15, quad = lane >> 4;
  const size_t Ab = (size_t)blockIdx.y * nkt * 512;
  const size_t Wb = (size_t)blockIdx.x * nkt * 512;

  if (t < 128) cntL[t] = 0u;

  f32x4 acc[4][4];
#pragma unroll
  for (int i = 0; i < 4; ++i)
#pragma unroll
    for (int j = 0; j < 4; ++j) acc[i][j] = (f32x4){0.f, 0.f, 0.f, 0.f};

  for (int kt = 0; kt < nkt; ++kt) {
    __syncthreads();
    const bf16x8* ag = A + Ab + (size_t)kt * 512 + wv * 128;
    const bf16x8* wg = W + Wb + (size_t)kt * 512 + wv * 128;
    bf16x8* al = As + wv * 128;
    bf16x8* wl = Ws + wv * 128;
    gload16(ag + lane, al);
    gload16(ag + 64 + lane, al + 64);
    gload16(wg + lane, wl);
    gload16(wg + 64 + lane, wl + 64);
    __syncthreads();
    bf16x8 af[4];
#pragma unroll
    for (int i = 0; i < 4; ++i) af[i] = As[quad * 128 + wm + i * 16 + lrow];
#pragma unroll
    for (int j = 0; j < 4; ++j) {
      bf16x8 bfr = Ws[quad * 128 + wn + j * 16 + lrow];
#pragma unroll
      for (int i = 0; i < 4; ++i)
        acc[i][j] = __builtin_amdgcn_mfma_f32_16x16x32_bf16(af[i], bfr, acc[i][j], 0, 0, 0);
    }
  }
  const int bf0 = blockIdx.x * 128, bb = blockIdx.y * 128;
#pragma unroll
  for (int j = 0; j < 4; ++j) {
    const int col = bf0 + wn + j * 16 + lrow;
    const float bc = benc[col];
#pragma unroll
    for (int i = 0; i < 4; ++i) {
      const int row0 = bb + wm + i * 16 + quad * 4;
#pragma unroll
      for (int rg = 0; rg < 4; ++rg) {
        float v = acc[i][j][rg] + bc;
        v = v > 0.f ? v : 0.f;
        const __bf16 hb = (__bf16)v;
        pre[(size_t)(row0 + rg) * F + col] = hb;
        const unsigned ub = (unsigned)bf16_bits(hb);
        const float vb = __uint_as_float(ub << 16);
        if (vb > TK_THR) {
          const int rl = row0 + rg - bb;  // local row 0..127
          const unsigned p = atomicAdd(&cntL[rl], 1u);
          if (p < ROWCAP) candL[rl * ROWCAP + p] = (ub << 16) | (unsigned)col;
        }
      }
    }
  }
  __syncthreads();
  if (t < 128) {
    const int r = bb + t;
    const unsigned nb = cntL[t];
    if (nb > ROWCAP) {
      atomicAdd(&cnt[r], (unsigned)(TK_CAP + 1));  // poison -> exact fallback
    } else if (nb > 0) {
      const unsigned base = atomicAdd(&cnt[r], nb);
      for (unsigned q = 0; q < nb; ++q) {
        const unsigned pos = base + q;
        if (pos < TK_CAP) cand[(size_t)r * TK_CAP + pos] = candL[t * ROWCAP + q];
      }
    }
  }
}

// ---------------------------------------------------------------------------
// topk_sel2: top-64 selection matching exact-fp64 ranking, from the
// precollected candidate list (fast path; no pre re-read).
//  1. load n<=2048 packed (bf16bits<<16|col) candidates (coalesced)
//  2. 2x8-bit radix over the 16 meaningful bits -> T = 64th-largest approx
//     (bin search = wave-parallel suffix scan, not serial 256-bin walk)
//  3. margin check: collection thr < T-eps certifies list completeness
//  4. > T+eps: sure-in, emit approx; [T-eps,T+eps]: exact fp64 rerank
// Fallback (n<64 / n>cap / margin fail): adaptive-threshold rescan of pre16,
// identical semantics to the round-0 passing kernel.
// ---------------------------------------------------------------------------
__global__ __launch_bounds__(TPB) void topk_sel2(
    const unsigned* __restrict__ cnt, const unsigned* __restrict__ cand,
    const unsigned short* __restrict__ pre,  // [B,F] bf16 bits (fallback only)
    const float* __restrict__ x, const float* __restrict__ W,
    const float* __restrict__ benc, const float* __restrict__ bdec,
    float* __restrict__ vals, int* __restrict__ idxs, int D, int F) {
  const int b = blockIdx.x;
  const int tid = threadIdx.x;

  __shared__ unsigned cpack[TK_CAP];
  __shared__ unsigned hist[256];
  __shared__ double xs[768];
  __shared__ int bcand[BAND_CAP];
  __shared__ double bexact[BAND_CAP];
  __shared__ int sh_cnt, sh_out, sh_band;
  __shared__ unsigned sh_prefix, sh_need;
  __shared__ float sh_thr;

  for (int d = tid; d < D; d += TPB)
    xs[d] = (double)x[(size_t)b * D + d] - (double)bdec[d];

  int n = 0;
  bool have = false;
  {
    const int nc = (int)cnt[b];
    if (nc >= 64 && nc <= TK_CAP) {
      for (int q = tid; q < nc; q += TPB) cpack[q] = cand[(size_t)b * TK_CAP + q];
      n = nc;
      have = true;
    }
  }
  if (tid == 0) sh_thr = TK_THR;
  __syncthreads();

  float T = 0.f;
  float step = 0.375f;
  for (int outer = 0; outer < 40; ++outer) {
    if (!have) {
      // fallback rescan (statistically unreachable for this data)
      const unsigned short* row = pre + (size_t)b * F;
      for (int tries = 0; tries < 40; ++tries) {
        if (tid == 0) sh_cnt = 0;
        __syncthreads();
        const float thr = sh_thr;
        for (int i = tid * 8; i < F; i += TPB * 8) {
          const uint4 pk = *(const uint4*)(row + i);
          const unsigned wb[4] = {pk.x, pk.y, pk.z, pk.w};
#pragma unroll
          for (int u = 0; u < 4; ++u) {
            const unsigned lo = wb[u] << 16;
            const unsigned hi = wb[u] & 0xFFFF0000u;
            if (__uint_as_float(lo) > thr) {
              int p = atomicAdd(&sh_cnt, 1);
              if (p < TK_CAP) cpack[p] = lo | (unsigned)(i + 2 * u);
            }
            if (__uint_as_float(hi) > thr) {
              int p = atomicAdd(&sh_cnt, 1);
              if (p < TK_CAP) cpack[p] = hi | (unsigned)(i + 2 * u + 1);
            }
          }
        }
        __syncthreads();
        n = sh_cnt;
        if (n >= 64 && n <= TK_CAP) break;
        if (tid == 0) sh_thr = (n < 64) ? sh_thr - step : sh_thr + step;
        step *= 0.5f;
        __syncthreads();
      }
      if (n > TK_CAP) n = TK_CAP;  // hang-safety clamp
    }

    // radix-select 64th largest over top-16 value bits (2 passes of 8)
    if (tid == 0) { sh_prefix = 0u; sh_need = 64u; }
#pragma unroll
    for (int pass = 0; pass < 2; ++pass) {
      const int shift = 24 - 8 * pass;
      hist[tid] = 0u;
      __syncthreads();
      const unsigned prefix = sh_prefix;
      const unsigned maskhi = pass == 0 ? 0u : 0xFF000000u;
      for (int q = tid; q < n; q += TPB) {
        const unsigned k = cpack[q];
        if ((k & maskhi) == prefix) atomicAdd(&hist[(k >> shift) & 255u], 1u);
      }
      __syncthreads();
      if (tid < 64) {
        // wave-parallel suffix scan: lane owns bins [4*tid, 4*tid+3]
        const unsigned h0 = hist[tid * 4], h1 = hist[tid * 4 + 1];
        const unsigned h2 = hist[tid * 4 + 2], h3 = hist[tid * 4 + 3];
        const unsigned lsum = h0 + h1 + h2 + h3;
        unsigned s = lsum;
#pragma unroll
        for (int off = 1; off < 64; off <<= 1) {
          const unsigned o = __shfl_down(s, off, 64);
          if (tid + off < 64) s += o;
        }
        const unsigned above = s - lsum;  // sum over lanes > tid
        const unsigned t3 = h3, t2 = h2 + t3, t1 = h1 + t2, t0 = h0 + t1;
        const unsigned suf[4] = {above + t0, above + t1, above + t2, above + t3};
        const unsigned hh[4] = {h0, h1, h2, h3};
        const unsigned need = sh_need;
#pragma unroll
        for (int u = 0; u < 4; ++u) {
          if (suf[u] >= need && suf[u] - hh[u] < need) {
            sh_prefix = prefix | ((unsigned)(tid * 4 + u) << shift);
            sh_need = need - (suf[u] - hh[u]);
          }
        }
      }
      __syncthreads();
    }
    T = __uint_as_float(sh_prefix);
    const float colthr = sh_thr;
    if (colthr < T - TK_EPS) break;  // completeness margin certified
    have = false;
    if (tid == 0) sh_thr = T - 2.f * TK_EPS;
    __syncthreads();
  }

  // classify collected
  if (tid == 0) { sh_out = 0; sh_band = 0; }
  __syncthreads();
  const float hicut = T + TK_EPS, locut = T - TK_EPS;
  float* ovals = vals + (size_t)b * 64;
  int* oidx = idxs + (size_t)b * 64;
  for (int q = tid; q < n; q += TPB) {
    const unsigned k = cpack[q];
    const float v = __uint_as_float(k & 0xFFFF0000u);
    const int id = (int)(k & 0xFFFFu);
    if (v > hicut) {
      int p = atomicAdd(&sh_out, 1);
      ovals[p] = v; oidx[p] = id;
    } else if (v >= locut) {
      int p = atomicAdd(&sh_band, 1);
      if (p < BAND_CAP) bcand[p] = id;
    }
  }
  __syncthreads();
  const int s = sh_out;
  const int bn = sh_band < BAND_CAP ? sh_band : BAND_CAP;
  const int needk = 64 - s;
  const int lane = tid & 63, wv = tid >> 6;
  for (int q = wv; q < bn; q += 4) {
    double sum = dot_w64(xs, W + (size_t)bcand[q] * D, lane, D);
    if (lane == 0) {
      double v = sum + (double)benc[bcand[q]];
      bexact[q] = v > 0.0 ? v : 0.0;
    }
  }
  __syncthreads();
  if (tid < bn) {
    const double v = bexact[tid];
    const int id = bcand[tid];
    int rank = 0;
    for (int j = 0; j < bn; ++j)
      rank += (bexact[j] > v) || (bexact[j] == v && bcand[j] < id);
    if (rank < needk) { ovals[s + rank] = (float)v; oidx[s + rank] = id; }
  }
}

// ---------------------------------------------------------------------------
// Transpose W_dec (D,F) -> (F,D)
// ---------------------------------------------------------------------------
__global__ __launch_bounds__(TPB) void transpose_df(
    const float* __restrict__ in, float* __restrict__ out, int D, int F) {
  __shared__ float tile[32][33];
  const int f0 = blockIdx.x * 32;
  const int d0 = blockIdx.y * 32;
  const int tx = threadIdx.x & 31;
  const int ty = threadIdx.x >> 5;
#pragma unroll
  for (int i = 0; i < 4; ++i)
    tile[ty + i * 8][tx] = in[(size_t)(d0 + ty + i * 8) * F + f0 + tx];
  __syncthreads();
#pragma unroll
  for (int i = 0; i < 4; ++i)
    out[(size_t)(f0 + ty + i * 8) * D + d0 + tx] = tile[tx][ty + i * 8];
}

// ---------------------------------------------------------------------------
// Sparse decode (float4): out[b,:] = bdec + sum_k vals[b,k] * WT[idx[b,k],:]
// ---------------------------------------------------------------------------
__global__ __launch_bounds__(TPB) void decode64(
    const float* __restrict__ WT, const float* __restrict__ bdec,
    const float* __restrict__ vals, const int* __restrict__ idxs,
    float* __restrict__ out, int D) {
  const int b = blockIdx.x;
  __shared__ float sv[64];
  __shared__ int si[64];
  const int tid = threadIdx.x;
  if (tid < 64) {
    sv[tid] = vals[(size_t)b * 64 + tid];
    si[tid] = idxs[(size_t)b * 64 + tid];
  }
  __syncthreads();
  const int nd4 = D >> 2;
  for (int d4 = tid; d4 < nd4; d4 += TPB) {
    f32x4 acc = *(const f32x4*)(bdec + d4 * 4);
#pragma unroll 8
    for (int k = 0; k < 64; ++k)
      acc += *(const f32x4*)(WT + (size_t)si[k] * D + d4 * 4) * sv[k];
    *(f32x4*)(out + (size_t)b * D + d4 * 4) = acc;
  }
}

// ---------------------------------------------------------------------------
// approx_acts: connection matching + wave-parallel cooperative dots
// ---------------------------------------------------------------------------
__global__ __launch_bounds__(TPB) void contrib(
    const int* __restrict__ conn, const float* __restrict__ Wencd,
    const float* __restrict__ WTdecu,
    const float* __restrict__ up_vals, const int* __restrict__ up_idx,
    const int* __restrict__ down_idx,
    float* __restrict__ approx, int D, int C) {
  const int b = blockIdx.x;
  __shared__ int sui[64];
  __shared__ float suv[64];
  __shared__ int sdi[64];
  __shared__ float sacc[64];
  __shared__ int queue[2048];
  __shared__ int qn;
  const int tid = threadIdx.x;
  if (tid < 64) {
    sui[tid] = up_idx[(size_t)b * 64 + tid];
    suv[tid] = up_vals[(size_t)b * 64 + tid];
    sdi[tid] = down_idx[(size_t)b * 64 + tid];
    sacc[tid] = 0.0f;
  }
  if (tid == 0) qn = 0;
  __syncthreads();
  const int npairs = 64 * C;
  for (int p = tid; p < npairs; p += TPB) {
    int kd = p / C, c = p - kd * C;
    int f = conn[(size_t)sdi[kd] * C + c];
    if (f < 0) continue;
    for (int ku = 0; ku < 64; ++ku) {
      if (sui[ku] == f) {  // up_idx distinct -> at most one match
        int q = atomicAdd(&qn, 1);
        queue[q] = (kd << 8) | ku;
        break;
      }
    }
  }
  __syncthreads();
  const int n = qn;
  const int lane = tid & 63, wv = tid >> 6;
  for (int q = wv; q < n; q += 4) {
    const int kd = queue[q] >> 8, ku = queue[q] & 255;
    float s = dotf_w64(Wencd + (size_t)sdi[kd] * D,
                       WTdecu + (size_t)sui[ku] * D, lane, D);
    if (lane == 0) atomicAdd(&sacc[kd], suv[ku] * s);
  }
  __syncthreads();
  if (tid < 64) approx[(size_t)b * 64 + tid] = sacc[tid];
}

// ---------------------------------------------------------------------------
extern "C" void kernel_launch(void* const* d_in, const int* in_sizes, int n_in,
                              void* d_out, int out_size, void* d_ws, size_t ws_size,
                              hipStream_t stream) {
  const float* x_up   = (const float*)d_in[0];
  const float* x_down = (const float*)d_in[1];
  const float* Wenc_u = (const float*)d_in[2];
  const float* benc_u = (const float*)d_in[3];
  const float* Wdec_u = (const float*)d_in[4];
  const float* bdec_u = (const float*)d_in[5];
  const float* Wenc_d = (const float*)d_in[6];
  const float* benc_d = (const float*)d_in[7];
  const float* Wdec_d = (const float*)d_in[8];
  const float* bdec_d = (const float*)d_in[9];
  const int*   conn   = (const int*)d_in[10];

  const int D = in_sizes[5];           // 768
  const int B = in_sizes[0] / D;       // 1024
  const int F = in_sizes[3];           // 24576
  const int C = in_sizes[10] / F;      // 32
  const int nkt = D / 32;              // 24

  float* out = (float*)d_out;
  char* w = (char*)d_ws;

  __bf16* pre16 = (__bf16*)w;
  bf16x8* Wperm = (bf16x8*)(w + (size_t)B * F * 2);
  bf16x8* xuP   = (bf16x8*)(w + (size_t)B * F * 2 + (size_t)F * D * 2);
  bf16x8* xdP   = xuP + (size_t)B * D / 8;
  float* up_vals = (float*)(xdP + (size_t)B * D / 8);
  int*   up_idx  = (int*)(up_vals + (size_t)B * 64);
  float* dn_vals = (float*)(up_idx + (size_t)B * 64);
  int*   dn_idx  = (int*)(dn_vals + (size_t)B * 64);
  float* approx  = (float*)(dn_idx + (size_t)B * 64);
  unsigned* cnt  = (unsigned*)(approx + (size_t)B * 64);   // [B]
  unsigned* cand = cnt + B;                                // [B][TK_CAP]
  float* WT = (float*)w;  // reuses pre+Wperm region after both are dead

  dim3 packW_grid(F / 128, nkt);
  dim3 packX_grid(B / 128, nkt);
  dim3 gemm_grid(F / 128, B / 128);
  dim3 tr_grid(F / 32, D / 32);

  // ---- upstream encode ----
  pack_tiles<<<packX_grid, TPB, 0, stream>>>(x_up, bdec_u, xuP, D, cnt, B);
  pack_tiles<<<packW_grid, TPB, 0, stream>>>(Wenc_u, nullptr, Wperm, D, nullptr, 0);
  enc_gemm_bf<<<gemm_grid, TPB, 0, stream>>>(xuP, Wperm, benc_u, pre16, cnt, cand, nkt, F);
  topk_sel2<<<B, TPB, 0, stream>>>(cnt, cand, (const unsigned short*)pre16, x_up,
                                   Wenc_u, benc_u, bdec_u, up_vals, up_idx, D, F);
  // ---- downstream encode ----
  pack_tiles<<<packX_grid, TPB, 0, stream>>>(x_down, bdec_d, xdP, D, cnt, B);
  pack_tiles<<<packW_grid, TPB, 0, stream>>>(Wenc_d, nullptr, Wperm, D, nullptr, 0);
  enc_gemm_bf<<<gemm_grid, TPB, 0, stream>>>(xdP, Wperm, benc_d, pre16, cnt, cand, nkt, F);
  topk_sel2<<<B, TPB, 0, stream>>>(cnt, cand, (const unsigned short*)pre16, x_down,
                                   Wenc_d, benc_d, bdec_d, dn_vals, dn_idx, D, F);

  // ---- decode + contributions ----
  transpose_df<<<tr_grid, TPB, 0, stream>>>(Wdec_u, WT, D, F);
  decode64<<<B, TPB, 0, stream>>>(WT, bdec_u, up_vals, up_idx, out, D);
  contrib<<<B, TPB, 0, stream>>>(conn, Wenc_d, WT, up_vals, up_idx, dn_idx,
                                 approx, D, C);
  transpose_df<<<tr_grid, TPB, 0, stream>>>(Wdec_d, WT, D, F);
  decode64<<<B, TPB, 0, stream>>>(WT, bdec_d, approx, dn_idx, out + (size_t)B * D, D);
}